// Round 1
// baseline (1369.398 us; speedup 1.0000x reference)
//
#include <hip/hip_runtime.h>
#include <hip/hip_bf16.h>

#define U_CNT 50000
#define I_CNT 25000
#define D_DIM 64
#define N_CNT 75000
#define E_CNT 2000000
#define B_CNT 4096

// ---------------------------------------------------------------------------
// init: acc = cur = concat(emb_user, emb_item); nxt = 0   (float4-vectorized)
// ---------------------------------------------------------------------------
__global__ void init_kernel(const float4* __restrict__ eu, const float4* __restrict__ ei,
                            float4* __restrict__ acc, float4* __restrict__ cur,
                            float4* __restrict__ nxt) {
    int i = blockIdx.x * blockDim.x + threadIdx.x;
    const int total = N_CNT * D_DIM / 4;   // 1,200,000
    const int ucut  = U_CNT * D_DIM / 4;   //   800,000
    if (i < total) {
        float4 v = (i < ucut) ? eu[i] : ei[i - ucut];
        acc[i] = v;
        cur[i] = v;
        nxt[i] = make_float4(0.f, 0.f, 0.f, 0.f);
    }
}

// ---------------------------------------------------------------------------
// SpMM: y[row] += vals * x[col]   — wave per edge, lane = dim.
// Edge metadata loaded coalesced (64 edges per wave iteration), broadcast via shfl.
// ---------------------------------------------------------------------------
__global__ void spmm_atomic(const float* __restrict__ vals, const int* __restrict__ row,
                            const int* __restrict__ col, const float* __restrict__ x,
                            float* __restrict__ y) {
    const int lane = threadIdx.x & 63;
    const int wid  = (blockIdx.x * blockDim.x + threadIdx.x) >> 6;
    const int nw   = (gridDim.x * blockDim.x) >> 6;
    const int ngroups = E_CNT / 64;        // 31250, exact
    for (int g = wid; g < ngroups; g += nw) {
        const int e = g * 64 + lane;
        const int   r = row[e];
        const int   c = col[e];
        const float v = vals[e];
        for (int j = 0; j < 64; ++j) {
            const int   rr = __shfl(r, j);
            const int   cc = __shfl(c, j);
            const float vv = __shfl(v, j);
            unsafeAtomicAdd(&y[rr * D_DIM + lane], vv * x[cc * D_DIM + lane]);
        }
    }
}

// ---------------------------------------------------------------------------
// acc += nxt; zero the buffer that becomes the next SpMM output
// ---------------------------------------------------------------------------
__global__ void add_zero(float4* __restrict__ acc, const float4* __restrict__ nxt,
                         float4* __restrict__ zbuf) {
    int i = blockIdx.x * blockDim.x + threadIdx.x;
    const int total = N_CNT * D_DIM / 4;
    if (i < total) {
        float4 a = acc[i], nx = nxt[i];
        a.x += nx.x; a.y += nx.y; a.z += nx.z; a.w += nx.w;
        acc[i] = a;
        zbuf[i] = make_float4(0.f, 0.f, 0.f, 0.f);
    }
}

// ---------------------------------------------------------------------------
// epilogue: one wave per batch element.
//   ue/ie = (acc[row] + last[row]) / 4        (fuses the 3rd acc += layer3)
//   pu = w_user @ ue ; pi = w_item @ ie       (lane d owns output dim d)
//   gamma = 0.5 * sum(softmax(pu) * sigmoid(pi)) + 0.5 * sigmoid(xij_emb)
// ---------------------------------------------------------------------------
__global__ void final_kernel(const float* __restrict__ acc, const float* __restrict__ last,
                             const float* __restrict__ w_user, const float* __restrict__ w_item,
                             const float* __restrict__ xij0, const float* __restrict__ xij1,
                             const int* __restrict__ users, const int* __restrict__ items,
                             const int* __restrict__ xij, float* __restrict__ out) {
    const int lane = threadIdx.x & 63;
    const int b = (blockIdx.x * blockDim.x + threadIdx.x) >> 6;
    if (b >= B_CNT) return;
    const int u  = users[b];
    const int it = items[b];
    const int ur = u * D_DIM;
    const int ir = (U_CNT + it) * D_DIM;
    const float ue = (acc[ur + lane] + last[ur + lane]) * 0.25f;
    const float ie = (acc[ir + lane] + last[ir + lane]) * 0.25f;

    float pu = 0.f, pi = 0.f;
    const float* wu = w_user + lane * D_DIM;
    const float* wi = w_item + lane * D_DIM;
    #pragma unroll
    for (int k = 0; k < 64; ++k) {
        const float uk = __shfl(ue, k);
        const float ik = __shfl(ie, k);
        pu = fmaf(wu[k], uk, pu);
        pi = fmaf(wi[k], ik, pi);
    }

    // softmax over 64 lanes
    float m = pu;
    for (int off = 32; off; off >>= 1) m = fmaxf(m, __shfl_xor(m, off));
    const float epu = __expf(pu - m);
    float s = epu;
    for (int off = 32; off; off >>= 1) s += __shfl_xor(s, off);
    const float soft = epu / s;

    const float sig = 1.f / (1.f + __expf(-pi));
    float prod = 0.5f * soft * sig;
    for (int off = 32; off; off >>= 1) prod += __shfl_xor(prod, off);

    if (lane == 0) {
        const float xe = xij[b] ? xij1[it] : xij0[it];
        const float sx = 1.f / (1.f + __expf(-xe));
        out[b] = prod + 0.5f * sx;
    }
}

// ---------------------------------------------------------------------------
extern "C" void kernel_launch(void* const* d_in, const int* in_sizes, int n_in,
                              void* d_out, int out_size, void* d_ws, size_t ws_size,
                              hipStream_t stream) {
    const float* emb_user  = (const float*)d_in[0];
    const float* emb_item  = (const float*)d_in[1];
    const float* xij0      = (const float*)d_in[2];
    const float* xij1      = (const float*)d_in[3];
    const float* w_user    = (const float*)d_in[4];
    const float* w_item    = (const float*)d_in[5];
    const float* edge_vals = (const float*)d_in[6];
    const int*   edge_row  = (const int*)d_in[7];
    const int*   edge_col  = (const int*)d_in[8];
    const int*   users     = (const int*)d_in[9];
    const int*   items     = (const int*)d_in[10];
    const int*   xij       = (const int*)d_in[11];
    float* out = (float*)d_out;

    float* acc  = (float*)d_ws;
    float* bufA = acc  + (size_t)N_CNT * D_DIM;
    float* bufB = bufA + (size_t)N_CNT * D_DIM;

    const int total4 = N_CNT * D_DIM / 4;
    dim3 blk(256);
    dim3 grd((total4 + 255) / 256);
    init_kernel<<<grd, blk, 0, stream>>>((const float4*)emb_user, (const float4*)emb_item,
                                         (float4*)acc, (float4*)bufA, (float4*)bufB);

    dim3 sgrid(2048);   // 8192 waves, grid-stride over 31250 edge-groups
    // layer 1: bufB = G * bufA ; acc += bufB ; zero bufA
    spmm_atomic<<<sgrid, blk, 0, stream>>>(edge_vals, edge_row, edge_col, bufA, bufB);
    add_zero<<<grd, blk, 0, stream>>>((float4*)acc, (const float4*)bufB, (float4*)bufA);
    // layer 2: bufA = G * bufB ; acc += bufA ; zero bufB
    spmm_atomic<<<sgrid, blk, 0, stream>>>(edge_vals, edge_row, edge_col, bufB, bufA);
    add_zero<<<grd, blk, 0, stream>>>((float4*)acc, (const float4*)bufA, (float4*)bufB);
    // layer 3: bufB = G * bufA ; (acc += bufB fused into epilogue)
    spmm_atomic<<<sgrid, blk, 0, stream>>>(edge_vals, edge_row, edge_col, bufA, bufB);

    final_kernel<<<dim3(B_CNT * 64 / 256), blk, 0, stream>>>(acc, bufB, w_user, w_item,
                                                             xij0, xij1, users, items, xij, out);
}

// Round 3
// 624.607 us; speedup vs baseline: 2.1924x; 2.1924x over previous
//
#include <hip/hip_runtime.h>
#include <hip/hip_bf16.h>

#define U_CNT 50000
#define I_CNT 25000
#define D_DIM 64
#define N_CNT 75000
#define E_CNT 2000000
#define B_CNT 4096
#define NBLK_SCAN ((N_CNT + 255) / 256)   // 293

// ---------------------------------------------------------------------------
// CSR build: histogram -> block scan -> bsum scan -> add offsets -> scatter
// rowptr buffer doubles as the histogram buffer (scan is in-place safe).
// ---------------------------------------------------------------------------
__global__ void hist_kernel(const int* __restrict__ row, int* __restrict__ cnt) {
    int e = blockIdx.x * blockDim.x + threadIdx.x;
    if (e < E_CNT) atomicAdd(&cnt[row[e]], 1);
}

__global__ void scan_block(int* __restrict__ data, int* __restrict__ bsum) {
    __shared__ int tmp[256];
    int i = blockIdx.x * 256 + threadIdx.x;
    int v = (i < N_CNT) ? data[i] : 0;
    tmp[threadIdx.x] = v;
    __syncthreads();
    for (int off = 1; off < 256; off <<= 1) {
        int t = (threadIdx.x >= off) ? tmp[threadIdx.x - off] : 0;
        __syncthreads();
        tmp[threadIdx.x] += t;
        __syncthreads();
    }
    if (i < N_CNT) data[i] = tmp[threadIdx.x] - v;   // exclusive within block
    if (threadIdx.x == 255) bsum[blockIdx.x] = tmp[255];
}

__global__ void scan_bsum(int* __restrict__ bsum) {
    __shared__ int tmp[512];
    int v = (threadIdx.x < NBLK_SCAN) ? bsum[threadIdx.x] : 0;
    tmp[threadIdx.x] = v;
    __syncthreads();
    for (int off = 1; off < 512; off <<= 1) {
        int t = (threadIdx.x >= off) ? tmp[threadIdx.x - off] : 0;
        __syncthreads();
        tmp[threadIdx.x] += t;
        __syncthreads();
    }
    if (threadIdx.x < NBLK_SCAN) bsum[threadIdx.x] = tmp[threadIdx.x] - v;  // exclusive
}

__global__ void add_off(int* __restrict__ rowptr, const int* __restrict__ bsum,
                        int* __restrict__ cursor) {
    int i = blockIdx.x * 256 + threadIdx.x;
    if (i < N_CNT) {
        int p = rowptr[i] + bsum[i >> 8];
        rowptr[i] = p;
        cursor[i] = p;
    }
    if (i == 0) rowptr[N_CNT] = E_CNT;
}

__global__ void scatter_kernel(const float* __restrict__ vals, const int* __restrict__ row,
                               const int* __restrict__ col, int* __restrict__ cursor,
                               int2* __restrict__ pk) {
    int e = blockIdx.x * blockDim.x + threadIdx.x;
    if (e < E_CNT) {
        int p = atomicAdd(&cursor[row[e]], 1);
        pk[p] = make_int2(col[e], __float_as_int(vals[e]));
    }
}

// ---------------------------------------------------------------------------
// Gather one CSR row segment: lane = dim. Edge (col,val) pairs loaded
// coalesced 64-at-a-time (8B each), broadcast via shfl; x gather is one
// coalesced 256B row read per edge.
// ---------------------------------------------------------------------------
__device__ __forceinline__ float row_gather(int s, int en, int lane,
                                            const int2* __restrict__ pk,
                                            const float* __restrict__ x) {
    float a = 0.f;
    for (int base = s; base < en; base += 64) {
        int k = base + lane;
        int2 p = (k < en) ? pk[k] : make_int2(0, 0);
        int m = min(64, en - base);
        for (int j = 0; j < m; ++j) {
            int   c = __shfl(p.x, j);
            float v = __int_as_float(__shfl(p.y, j));
            a = fmaf(v, x[c * D_DIM + lane], a);
        }
    }
    return a;
}

// layer 1: x = concat(emb_user, emb_item) read in place; acc = emb + l1; y = l1
__global__ void spmm_layer1(const int* __restrict__ rowptr, const int2* __restrict__ pk,
                            const float* __restrict__ eu, const float* __restrict__ ei,
                            float* __restrict__ y, float* __restrict__ acc) {
    const int lane = threadIdx.x & 63;
    const int r = (blockIdx.x * blockDim.x + threadIdx.x) >> 6;
    if (r >= N_CNT) return;
    const int s = rowptr[r], en = rowptr[r + 1];
    float a = 0.f;
    for (int base = s; base < en; base += 64) {
        int k = base + lane;
        int2 p = (k < en) ? pk[k] : make_int2(0, 0);
        int m = min(64, en - base);
        for (int j = 0; j < m; ++j) {
            int   c = __shfl(p.x, j);
            float v = __int_as_float(__shfl(p.y, j));
            const float* xp = (c < U_CNT) ? (eu + (size_t)c * D_DIM)
                                          : (ei + (size_t)(c - U_CNT) * D_DIM);
            a = fmaf(v, xp[lane], a);
        }
    }
    const float e0 = (r < U_CNT) ? eu[(size_t)r * D_DIM + lane]
                                 : ei[(size_t)(r - U_CNT) * D_DIM + lane];
    y[(size_t)r * D_DIM + lane] = a;
    acc[(size_t)r * D_DIM + lane] = e0 + a;
}

// layer 2: y = G*x ; acc += y
__global__ void spmm_layer2(const int* __restrict__ rowptr, const int2* __restrict__ pk,
                            const float* __restrict__ x, float* __restrict__ y,
                            float* __restrict__ acc) {
    const int lane = threadIdx.x & 63;
    const int r = (blockIdx.x * blockDim.x + threadIdx.x) >> 6;
    if (r >= N_CNT) return;
    const float a = row_gather(rowptr[r], rowptr[r + 1], lane, pk, x);
    y[(size_t)r * D_DIM + lane] = a;
    acc[(size_t)r * D_DIM + lane] += a;
}

// ---------------------------------------------------------------------------
// epilogue, one wave per batch element; layer-3 SpMM computed ONLY for the
// two rows this element needs (fused, ~11% of a full layer's work).
// ---------------------------------------------------------------------------
__global__ void final_kernel(const int* __restrict__ rowptr, const int2* __restrict__ pk,
                             const float* __restrict__ l2, const float* __restrict__ acc,
                             const float* __restrict__ w_user, const float* __restrict__ w_item,
                             const float* __restrict__ xij0, const float* __restrict__ xij1,
                             const int* __restrict__ users, const int* __restrict__ items,
                             const int* __restrict__ xij, float* __restrict__ out) {
    const int lane = threadIdx.x & 63;
    const int b = (blockIdx.x * blockDim.x + threadIdx.x) >> 6;
    if (b >= B_CNT) return;
    const int u  = users[b];
    const int it = items[b];
    const int ri = U_CNT + it;

    const float l3u = row_gather(rowptr[u],  rowptr[u + 1],  lane, pk, l2);
    const float l3i = row_gather(rowptr[ri], rowptr[ri + 1], lane, pk, l2);
    const float ue = (acc[(size_t)u  * D_DIM + lane] + l3u) * 0.25f;
    const float ie = (acc[(size_t)ri * D_DIM + lane] + l3i) * 0.25f;

    float pu = 0.f, pi = 0.f;
    const float* wu = w_user + lane * D_DIM;
    const float* wi = w_item + lane * D_DIM;
    #pragma unroll
    for (int k = 0; k < 64; ++k) {
        const float uk = __shfl(ue, k);
        const float ik = __shfl(ie, k);
        pu = fmaf(wu[k], uk, pu);
        pi = fmaf(wi[k], ik, pi);
    }

    // softmax over 64 lanes
    float m = pu;
    for (int off = 32; off; off >>= 1) m = fmaxf(m, __shfl_xor(m, off));
    const float epu = __expf(pu - m);
    float s = epu;
    for (int off = 32; off; off >>= 1) s += __shfl_xor(s, off);
    const float soft = epu / s;

    const float sig = 1.f / (1.f + __expf(-pi));
    float prod = 0.5f * soft * sig;
    for (int off = 32; off; off >>= 1) prod += __shfl_xor(prod, off);

    if (lane == 0) {
        const float xe = xij[b] ? xij1[it] : xij0[it];
        const float sx = 1.f / (1.f + __expf(-xe));
        out[b] = prod + 0.5f * sx;
    }
}

// ---------------------------------------------------------------------------
extern "C" void kernel_launch(void* const* d_in, const int* in_sizes, int n_in,
                              void* d_out, int out_size, void* d_ws, size_t ws_size,
                              hipStream_t stream) {
    const float* emb_user  = (const float*)d_in[0];
    const float* emb_item  = (const float*)d_in[1];
    const float* xij0      = (const float*)d_in[2];
    const float* xij1      = (const float*)d_in[3];
    const float* w_user    = (const float*)d_in[4];
    const float* w_item    = (const float*)d_in[5];
    const float* edge_vals = (const float*)d_in[6];
    const int*   edge_row  = (const int*)d_in[7];
    const int*   edge_col  = (const int*)d_in[8];
    const int*   users     = (const int*)d_in[9];
    const int*   items     = (const int*)d_in[10];
    const int*   xij       = (const int*)d_in[11];
    float* out = (float*)d_out;

    // workspace carve-up (all 4B types; ~75 MB total)
    float* acc    = (float*)d_ws;                          // N*D
    float* bufA   = acc  + (size_t)N_CNT * D_DIM;          // N*D
    float* bufB   = bufA + (size_t)N_CNT * D_DIM;          // N*D
    int2*  pk     = (int2*)(bufB + (size_t)N_CNT * D_DIM); // E  (8B each)
    int*   rowptr = (int*)(pk + (size_t)E_CNT);            // N+1
    int*   cursor = rowptr + (N_CNT + 1);                  // N
    int*   bsum   = cursor + N_CNT;                        // 512

    dim3 blk(256);

    // --- CSR build ---
    hipMemsetAsync(rowptr, 0, (N_CNT + 1) * sizeof(int), stream);
    hist_kernel<<<dim3((E_CNT + 255) / 256), blk, 0, stream>>>(edge_row, rowptr);
    scan_block<<<dim3(NBLK_SCAN), blk, 0, stream>>>(rowptr, bsum);
    scan_bsum<<<dim3(1), dim3(512), 0, stream>>>(bsum);
    add_off<<<dim3(NBLK_SCAN), blk, 0, stream>>>(rowptr, bsum, cursor);
    scatter_kernel<<<dim3((E_CNT + 255) / 256), blk, 0, stream>>>(edge_vals, edge_row,
                                                                  edge_col, cursor, pk);

    // --- 2 full SpMM layers (layer 3 fused into epilogue) ---
    dim3 sgrid((N_CNT * 64 + 255) / 256);   // one wave per row
    spmm_layer1<<<sgrid, blk, 0, stream>>>(rowptr, pk, emb_user, emb_item, bufA, acc);
    spmm_layer2<<<sgrid, blk, 0, stream>>>(rowptr, pk, bufA, bufB, acc);

    // --- fused layer-3 + epilogue ---
    final_kernel<<<dim3(B_CNT * 64 / 256), blk, 0, stream>>>(rowptr, pk, bufB, acc,
                                                             w_user, w_item, xij0, xij1,
                                                             users, items, xij, out);
}